// Round 12
// baseline (550.499 us; speedup 1.0000x reference)
//
#include <hip/hip_runtime.h>
#include <hip/hip_bf16.h>
#include <stdint.h>

#define B_     2048
#define WIN_   11
#define K_     4096
#define VOCAB_ 30522
#define NOUT_  18
#define TOPK_  64
#define NPAIR_ (B_ * WIN_)         /* 22528 */
#define PI_F   3.14159274101257324f

#define NCH_    16                 /* chunks per k-slice (power of 2) */
#define CHUNK_  1908               /* entries per chunk; 16*1908=30528 >= 30522 */
#define CUNITS_ 954                /* float4 units per full chunk */
#define TAILU_  951                /* units in chunk 15 (1902 entries) */
#define UPK_    15261              /* float4 units per k-slice */
#define BUFB_   (CHUNK_ * 8)       /* 15264 bytes per LDS buffer */
#define KPB_    16                 /* k per persistent block */
#define NBLK_   (K_ / KPB_)        /* 256 blocks = 1 per CU */
#define GTOT_   (NCH_ * KPB_)      /* 256 chunks per block */
#define NWIN_   (GTOT_ / 2)        /* 128 windows (2 chunks each) */
#define PFTH_   1024
#define PRT_    256                /* producer threads = waves 0..3 */
#define CNT_    768                /* consumer threads = waves 4..15 */
#define PCON_BYTES_ (NPAIR_ * 4)                 /* 90112 */
#define SMEM_BYTES_ (PCON_BYTES_ + 4 * BUFB_)    /* 151168 */

static_assert(NWIN_ % 2 == 0, "window ping-pong");

typedef float vf4 __attribute__((ext_vector_type(4)));

// ---------------------------------------------------------------------------
// Kernel A: per-batch window prep -> trig-table index per (b,w)
// ---------------------------------------------------------------------------
__global__ void prep_kernel(const int* __restrict__ ids, int* __restrict__ tabv) {
    int b = blockIdx.x * blockDim.x + threadIdx.x;
    if (b >= B_) return;
    const int* row = ids + b * WIN_;
    int poss[WIN_];
    int cnt = 0;
#pragma unroll
    for (int w = 0; w < WIN_; ++w) { cnt += (row[w] != 0); poss[w] = cnt; }
    int sl = (cnt > 0) ? cnt : WIN_;
#pragma unroll
    for (int w = 0; w < WIN_; ++w) {
        int tb = (poss[w] - 1) * 11 + (sl - 1);
        if (tb < 0) tb = 0;
        tabv[b * WIN_ + w] = tb;
    }
}

// ---------------------------------------------------------------------------
// Kernel A2: stable deterministic bucket-by-chunk of the 22528 (b,w) pairs.
// smeta[pos] = int2{ id, dst | (tab<<16) }; chunkstart[0..NCH_].
// ---------------------------------------------------------------------------
__global__ __launch_bounds__(512) void bucket_kernel(const int* __restrict__ ids,
                                                     const int* __restrict__ tabv,
                                                     int2* __restrict__ smeta,
                                                     int* __restrict__ chunkstart) {
    __shared__ int lcnt[512 * NCH_];
    __shared__ int segtot[NCH_][8];
    __shared__ int tot[NCH_];
    __shared__ int bbase[NCH_ + 1];
    const int t = threadIdx.x;

#pragma unroll
    for (int c = 0; c < NCH_; ++c) lcnt[t * NCH_ + c] = 0;
    __syncthreads();

    for (int p = t; p < NPAIR_; p += 512) {
        int id = ids[p];
        if (id != 0) lcnt[t * NCH_ + (id / CHUNK_)] += 1;
    }
    __syncthreads();

    if (t < NCH_ * 8) {
        int bkt = t >> 3, seg = t & 7;
        int run = 0;
        for (int i = 0; i < 64; ++i) {
            int idx = (seg * 64 + i) * NCH_ + bkt;
            int tmp = lcnt[idx];
            lcnt[idx] = run;
            run += tmp;
        }
        segtot[bkt][seg] = run;
    }
    __syncthreads();
    if (t < NCH_) {
        int run = 0;
#pragma unroll
        for (int s = 0; s < 8; ++s) { int tmp = segtot[t][s]; segtot[t][s] = run; run += tmp; }
        tot[t] = run;
    }
    __syncthreads();
    if (t == 0) {
        int run = 0;
#pragma unroll
        for (int c = 0; c < NCH_; ++c) { bbase[c] = run; run += tot[c]; }
        bbase[NCH_] = run;
#pragma unroll
        for (int c = 0; c <= NCH_; ++c) chunkstart[c] = bbase[c];
    }
    __syncthreads();
    if (t < NCH_ * 8) {
        int bkt = t >> 3, seg = t & 7;
        int add = segtot[bkt][seg];
        for (int i = 0; i < 64; ++i) lcnt[(seg * 64 + i) * NCH_ + bkt] += add;
    }
    __syncthreads();

    for (int p = t; p < NPAIR_; p += 512) {
        int id = ids[p];
        if (id == 0) continue;
        int bkt = id / CHUNK_;
        int pos = bbase[bkt] + lcnt[t * NCH_ + bkt];
        lcnt[t * NCH_ + bkt] += 1;
        int2 mm;
        mm.x = id;
        mm.y = p | (tabv[p] << 16);
        smeta[pos] = mm;
    }
}

// ---------------------------------------------------------------------------
// pair body: bit-identical arithmetic to all passing rounds
// ---------------------------------------------------------------------------
__device__ __forceinline__ void pair_body2(const int2 m, const float2* __restrict__ sb,
                                           int lo, const float2* __restrict__ trig,
                                           float* __restrict__ pcontrib) {
    int id  = m.x;
    int dst = m.y & 0xFFFF;
    int tab = m.y >> 16;
    float2 o = trig[tab];
    float2 g = sb[id - lo];
    float wabs = sqrtf(__fadd_rn(__fmul_rn(g.x, g.x), __fmul_rn(g.y, g.y)));
    float pre = __fadd_rn(__fmul_rn(g.x, o.x), __fmul_rn(g.y, o.y));
    float pim = __fsub_rn(__fmul_rn(g.y, o.x), __fmul_rn(g.x, o.y));
    if (pre < 1e-10f && pre > -1e-10f) pre = 1e-10f;
    if (pim < 1e-10f && pim > -1e-10f) pim = 1e-10f;
    float ang = fabsf(atan2f(pim, pre));
    pcontrib[dst] = __fadd_rn(wabs, ang);
}

// ---------------------------------------------------------------------------
// Kernel B: persistent, 1 block/CU, producer/consumer specialization.
// 2 chunks per barrier window (128 windows). R12 fix vs R11: __syncthreads()
// after cstart/trigS LDS init, BEFORE the prologue (R11's consumer prologue
// read cstart before any barrier -> race -> OOB LDS -> abort).
// ---------------------------------------------------------------------------
__global__ __launch_bounds__(PFTH_, 1) void pf_kernel(const vf4* __restrict__ W4,
                                                      const int2* __restrict__ smeta,
                                                      const int* __restrict__ chunkstart,
                                                      float* __restrict__ pfT) {
    extern __shared__ char smem[];
    float* pcontrib = (float*)smem;                        // [NPAIR_]
    char*  sbuf     = smem + PCON_BYTES_;                  // [4][BUFB_]
    __shared__ int cstart[NCH_ + 1];
    __shared__ float2 trigS[121];

    const int t = threadIdx.x;
    const int kbase = blockIdx.x * KPB_;

    if (t <= NCH_) cstart[t] = chunkstart[t];
    if (t < 121) {
        int pp = t / 11 + 1, ss = t % 11 + 1;
        float pos = __fdiv_rn(__fmul_rn(PI_F, (float)pp), (float)ss);
        trigS[t] = make_float2(cosf(pos), sinf(pos));
    }
    __syncthreads();   // R12 FIX: cstart/trigS visible to all waves before prologue

#define LOADCH(G, R0, R1, R2, R3)                                                \
    {   int g2_ = (G);                                                           \
        if (g2_ < GTOT_) {                                                       \
            int kk2_ = g2_ >> 4, cc2_ = g2_ & 15;                                \
            int nu2_ = (cc2_ == 15) ? TAILU_ : CUNITS_;                          \
            const vf4* s2_ = W4 + (size_t)(kbase + kk2_) * UPK_ + (size_t)cc2_ * CUNITS_; \
            R0 = __builtin_nontemporal_load(&s2_[t]);                            \
            R1 = __builtin_nontemporal_load(&s2_[256 + t]);                      \
            R2 = __builtin_nontemporal_load(&s2_[512 + t]);                      \
            if (768 + t < nu2_) R3 = __builtin_nontemporal_load(&s2_[768 + t]);  \
        }                                                                        \
    }

#define WRITECH(G, R0, R1, R2, R3)                                               \
    {   int g2_ = (G);                                                           \
        if (g2_ < GTOT_) {                                                       \
            int cc2_ = g2_ & 15;                                                 \
            int nu2_ = (cc2_ == 15) ? TAILU_ : CUNITS_;                          \
            vf4* db_ = (vf4*)(sbuf + (size_t)(g2_ & 3) * BUFB_);                 \
            db_[t] = R0; db_[256 + t] = R1; db_[512 + t] = R2;                   \
            if (768 + t < nu2_) db_[768 + t] = R3;                               \
        }                                                                        \
    }

#define SMLOAD(G, M0, M1, M2)                                                    \
    {   int cc2_ = (G) & 15;                                                     \
        int ns_ = cstart[cc2_];                                                  \
        int q0_ = ns_ + ct;            if (q0_ > NPAIR_ - 1) q0_ = NPAIR_ - 1;   \
        int q1_ = ns_ + CNT_ + ct;     if (q1_ > NPAIR_ - 1) q1_ = NPAIR_ - 1;   \
        int q2_ = ns_ + 2 * CNT_ + ct; if (q2_ > NPAIR_ - 1) q2_ = NPAIR_ - 1;   \
        M0 = smeta[q0_]; M1 = smeta[q1_]; M2 = smeta[q2_]; }

#define SMCOMP(G, M0, M1, M2)                                                    \
    {   int cc2_ = (G) & 15;                                                     \
        const float2* sb_ = (const float2*)(sbuf + (size_t)((G) & 3) * BUFB_);   \
        const int lo_ = cc2_ * CHUNK_;                                           \
        const int cs_ = cstart[cc2_], ce_ = cstart[cc2_ + 1];                    \
        if (cs_ + ct < ce_)           pair_body2(M0, sb_, lo_, trigS, pcontrib); \
        if (cs_ + CNT_ + ct < ce_)    pair_body2(M1, sb_, lo_, trigS, pcontrib); \
        if (cs_ + 2 * CNT_ + ct < ce_) pair_body2(M2, sb_, lo_, trigS, pcontrib);\
        for (int pp_ = cs_ + 3 * CNT_ + ct; pp_ < ce_; pp_ += CNT_)              \
            pair_body2(smeta[pp_], sb_, lo_, trigS, pcontrib); }

    // producer reg sets (2 chunks x 4 regs each), ping-pong a <-> b
    vf4 a0, a1, a2, a3, a4, a5, a6, a7;
    vf4 b0, b1, b2, b3, b4, b5, b6, b7;
    // consumer smeta sets (2 chunks x 3 regs each), ping-pong mA <-> mB
    int2 mA0{}, mA1{}, mA2{}, mA3{}, mA4{}, mA5{};
    int2 mB0{}, mB1{}, mB2{}, mB3{}, mB4{}, mB5{};
    const int ct = (t >= PRT_) ? (t - PRT_) : 0;

    // ---- prologue: chunks 0,1 -> buffers 0,1 (via set a); chunks 2,3 -> set b
    if (t < PRT_) {
        LOADCH(0, a0, a1, a2, a3)
        LOADCH(1, a4, a5, a6, a7)
        WRITECH(0, a0, a1, a2, a3)
        WRITECH(1, a4, a5, a6, a7)
        LOADCH(2, b0, b1, b2, b3)
        LOADCH(3, b4, b5, b6, b7)
    } else {
        SMLOAD(0, mA0, mA1, mA2)
        SMLOAD(1, mA3, mA4, mA5)
    }
    for (int i = t; i < NPAIR_; i += PFTH_) pcontrib[i] = 0.0f;
    asm volatile("s_waitcnt vmcnt(0) lgkmcnt(0)" ::: "memory");
    __builtin_amdgcn_s_barrier();
    __builtin_amdgcn_sched_barrier(0);

#define WINDOW(WJ, L0,L1,L2,L3,L4,L5,L6,L7, S0,S1,S2,S3,S4,S5,S6,S7,            \
               U0,U1,U2,U3,U4,U5, V0,V1,V2,V3,V4,V5)                             \
    {                                                                            \
        const int w_ = (WJ);                                                     \
        __builtin_amdgcn_sched_barrier(0);                                       \
        asm volatile("s_waitcnt lgkmcnt(0)" ::: "memory");                       \
        __builtin_amdgcn_s_barrier();                                            \
        __builtin_amdgcn_sched_barrier(0);                                       \
        if (t < PRT_) {                                                          \
            LOADCH(2 * w_ + 4, L0, L1, L2, L3)                                   \
            LOADCH(2 * w_ + 5, L4, L5, L6, L7)                                   \
            WRITECH(2 * w_ + 2, S0, S1, S2, S3)                                  \
            WRITECH(2 * w_ + 3, S4, S5, S6, S7)                                  \
        } else {                                                                 \
            SMLOAD(2 * w_ + 2, V0, V1, V2)                                       \
            SMLOAD(2 * w_ + 3, V3, V4, V5)                                       \
            SMCOMP(2 * w_,     U0, U1, U2)                                       \
            SMCOMP(2 * w_ + 1, U3, U4, U5)                                       \
        }                                                                        \
        if (((2 * w_ + 1) & 15) == 15) {                                         \
            __builtin_amdgcn_sched_barrier(0);                                   \
            asm volatile("s_waitcnt lgkmcnt(0)" ::: "memory");                    \
            __builtin_amdgcn_s_barrier();                                        \
            __builtin_amdgcn_sched_barrier(0);                                   \
            const int kk_ = (2 * w_) >> 4;                                       \
            float* outp_ = pfT + (size_t)(kbase + kk_) * B_;                     \
            _Pragma("unroll")                                                    \
            for (int i_ = 0; i_ < B_ / PFTH_; ++i_) {                            \
                int bb_ = i_ * PFTH_ + t;                                        \
                float acc_ = 0.0f;                                               \
                _Pragma("unroll")                                                \
                for (int ww_ = 0; ww_ < WIN_; ++ww_)                             \
                    acc_ = __fadd_rn(acc_, pcontrib[bb_ * WIN_ + ww_]);          \
                outp_[bb_] = acc_;                                               \
            }                                                                    \
        }                                                                        \
    }

#pragma unroll 1
    for (int w = 0; w < NWIN_; w += 2) {
        WINDOW(w,     a0,a1,a2,a3,a4,a5,a6,a7, b0,b1,b2,b3,b4,b5,b6,b7,
               mA0,mA1,mA2,mA3,mA4,mA5, mB0,mB1,mB2,mB3,mB4,mB5)
        WINDOW(w + 1, b0,b1,b2,b3,b4,b5,b6,b7, a0,a1,a2,a3,a4,a5,a6,a7,
               mB0,mB1,mB2,mB3,mB4,mB5, mA0,mA1,mA2,mA3,mA4,mA5)
    }
#undef WINDOW
#undef SMCOMP
#undef SMLOAD
#undef WRITECH
#undef LOADCH
}

// ---------------------------------------------------------------------------
// Kernel T: transpose [K,B] -> [B,K] via 64x64 LDS tiles
// ---------------------------------------------------------------------------
__global__ __launch_bounds__(256) void transpose_kb(const float* __restrict__ pfT,
                                                    float* __restrict__ pf) {
    __shared__ float tile[64][65];
    int kb = blockIdx.x * 64;
    int bb = blockIdx.y * 64;
    int tx = threadIdx.x & 63;
    int ty = threadIdx.x >> 6;
#pragma unroll
    for (int i = 0; i < 64; i += 4)
        tile[ty + i][tx] = pfT[(size_t)(kb + ty + i) * B_ + (bb + tx)];
    __syncthreads();
#pragma unroll
    for (int i = 0; i < 64; i += 4)
        pf[(size_t)(bb + ty + i) * K_ + (kb + tx)] = tile[tx][ty + i];
}

// ---------------------------------------------------------------------------
// Kernel C: per-row exact top-64 (radix select, jax tie semantics) + logits.
// ---------------------------------------------------------------------------
__global__ __launch_bounds__(256) void topk_logits_kernel(const float* __restrict__ pf,
                                                          const float* __restrict__ w_out,
                                                          const float* __restrict__ b_out,
                                                          float* __restrict__ out) {
    const int b = blockIdx.x;
    const int t = threadIdx.x;
    __shared__ uint32_t srow[K_];
    __shared__ int hist[256];
    __shared__ int sfx[256];
    __shared__ uint32_t sh_prefix;
    __shared__ int sh_need;
    __shared__ int wave_gt[4], wave_eq[4];
    __shared__ int gt_running, eq_running;
    __shared__ int idxlist[TOPK_];
    __shared__ float partial[4][NOUT_];

    const float* rowp = pf + (size_t)b * K_;
    for (int i = t; i < K_; i += 256) srow[i] = __float_as_uint(rowp[i]);
    if (t == 0) { sh_prefix = 0u; sh_need = TOPK_; gt_running = 0; eq_running = 0; }
    __syncthreads();

    for (int pass = 0; pass < 4; ++pass) {
        int shift = 24 - 8 * pass;
        uint32_t himask = (pass == 0) ? 0u : (0xFFFFFFFFu << (shift + 8));
        hist[t] = 0;
        __syncthreads();
        uint32_t prefix = sh_prefix & himask;
        for (int i = t; i < K_; i += 256) {
            uint32_t u = srow[i];
            if ((u & himask) == prefix) atomicAdd(&hist[(u >> shift) & 255], 1);
        }
        __syncthreads();
        sfx[t] = hist[t];
        __syncthreads();
#pragma unroll
        for (int off = 1; off < 256; off <<= 1) {
            int v = (t + off < 256) ? sfx[t + off] : 0;
            __syncthreads();
            sfx[t] += v;
            __syncthreads();
        }
        int need = sh_need;
        int above = (t == 255) ? 0 : sfx[t + 1];
        if (sfx[t] >= need && above < need) {
            sh_prefix |= ((uint32_t)t << shift);
            sh_need = need - above;
        }
        __syncthreads();
    }
    const uint32_t T = sh_prefix;
    const int r = sh_need;
    const int c_gt = TOPK_ - r;

    for (int cbase = 0; cbase < K_; cbase += 256) {
        uint32_t u = srow[cbase + t];
        bool gt = (u > T);
        bool eq = (u == T);
        unsigned long long mg = __ballot(gt);
        unsigned long long me = __ballot(eq);
        int lane = t & 63, wv = t >> 6;
        if (lane == 0) { wave_gt[wv] = __popcll(mg); wave_eq[wv] = __popcll(me); }
        __syncthreads();
        int offg = gt_running, offe = eq_running;
        for (int w2 = 0; w2 < wv; ++w2) { offg += wave_gt[w2]; offe += wave_eq[w2]; }
        unsigned long long lmask = (lane == 0) ? 0ull : ((~0ull) >> (64 - lane));
        int rkg = offg + __popcll(mg & lmask);
        int rke = offe + __popcll(me & lmask);
        if (gt) idxlist[rkg] = cbase + t;
        else if (eq && rke < r) idxlist[c_gt + rke] = cbase + t;
        __syncthreads();
        if (t == 0) {
            gt_running += wave_gt[0] + wave_gt[1] + wave_gt[2] + wave_gt[3];
            eq_running += wave_eq[0] + wave_eq[1] + wave_eq[2] + wave_eq[3];
        }
        __syncthreads();
    }

    {
        int lane = t & 63, wv4 = t >> 6;
        if (lane < NOUT_) {
            const float* wrow = w_out + (size_t)lane * K_;
            float s = 0.0f;
#pragma unroll
            for (int j = 0; j < TOPK_ / 4; ++j) s += wrow[idxlist[wv4 * (TOPK_ / 4) + j]];
            partial[wv4][lane] = s;
        }
        __syncthreads();
        if (t < NOUT_) {
            float s = b_out[t] + partial[0][t] + partial[1][t] + partial[2][t] + partial[3][t];
            out[b * NOUT_ + t] = s;
        }
    }
}

// ---------------------------------------------------------------------------
extern "C" void kernel_launch(void* const* d_in, const int* in_sizes, int n_in,
                              void* d_out, int out_size, void* d_ws, size_t ws_size,
                              hipStream_t stream) {
    const int*   ids   = (const int*)d_in[0];
    const float* W     = (const float*)d_in[1];
    const float* w_out = (const float*)d_in[2];
    const float* b_out = (const float*)d_in[3];
    float* out = (float*)d_out;

    char* ws = (char*)d_ws;
    const size_t pf_bytes = (size_t)K_ * B_ * sizeof(float);   // 33.55 MB
    float* pfT   = (float*)(ws);                               // [K, B]
    float* pf    = (float*)(ws + pf_bytes);                    // [B, K]
    int*   tabv  = (int*)(ws + 2 * pf_bytes);                  // [NPAIR_]
    int2*  smeta = (int2*)(ws + 2 * pf_bytes + 256 * 1024);    // [NPAIR_]
    int* chunkstart = (int*)(ws + 2 * pf_bytes + 768 * 1024);  // [NCH_+1]

    (void)hipFuncSetAttribute((const void*)pf_kernel,
                              hipFuncAttributeMaxDynamicSharedMemorySize,
                              SMEM_BYTES_);

    prep_kernel<<<(B_ + 255) / 256, 256, 0, stream>>>(ids, tabv);
    bucket_kernel<<<1, 512, 0, stream>>>(ids, tabv, smeta, chunkstart);
    pf_kernel<<<NBLK_, PFTH_, SMEM_BYTES_, stream>>>((const vf4*)W, smeta, chunkstart, pfT);
    transpose_kb<<<dim3(K_ / 64, B_ / 64), 256, 0, stream>>>(pfT, pf);
    topk_logits_kernel<<<B_, 256, 0, stream>>>(pf, w_out, b_out, out);
}

// Round 13
// 435.241 us; speedup vs baseline: 1.2648x; 1.2648x over previous
//
#include <hip/hip_runtime.h>
#include <hip/hip_bf16.h>
#include <stdint.h>

#define B_     2048
#define WIN_   11
#define K_     4096
#define VOCAB_ 30522
#define NOUT_  18
#define TOPK_  64
#define NPAIR_ (B_ * WIN_)         /* 22528 */
#define PI_F   3.14159274101257324f

#define NCH_    15                 /* chunks per k-slice */
#define CHUNK_  2048               /* entries = 16 KB */
#define UNITS_  1024               /* 16B units per full chunk */
#define TAILU_  925                /* 16B units in last chunk */
#define KPB_    16                 /* k per persistent block */
#define NBLK_   (K_ / KPB_)        /* 256 blocks = 1 per CU */
#define GTOT_   (NCH_ * KPB_)      /* 240 phases */
#define PFTH_   1024
#define PRT_    64                 /* producer = wave 0 only (DMA, no VGPR data) */
#define CNT_    960                /* consumer threads = waves 1..15 */
#define PCON_BYTES_ (NPAIR_ * 4)                    /* 90112 */
#define SMEM_BYTES_ (PCON_BYTES_ + 4 * CHUNK_ * 8)  /* 155648 (proven) */

static_assert(GTOT_ % 2 == 0, "2-phase ping-pong");

// ---------------------------------------------------------------------------
// Kernel A: per-batch window prep -> trig-table index per (b,w)
// ---------------------------------------------------------------------------
__global__ void prep_kernel(const int* __restrict__ ids, int* __restrict__ tabv) {
    int b = blockIdx.x * blockDim.x + threadIdx.x;
    if (b >= B_) return;
    const int* row = ids + b * WIN_;
    int poss[WIN_];
    int cnt = 0;
#pragma unroll
    for (int w = 0; w < WIN_; ++w) { cnt += (row[w] != 0); poss[w] = cnt; }
    int sl = (cnt > 0) ? cnt : WIN_;
#pragma unroll
    for (int w = 0; w < WIN_; ++w) {
        int tb = (poss[w] - 1) * 11 + (sl - 1);
        if (tb < 0) tb = 0;
        tabv[b * WIN_ + w] = tb;
    }
}

// ---------------------------------------------------------------------------
// Kernel A2: stable deterministic bucket-by-chunk of the 22528 (b,w) pairs.
// smeta[pos] = int2{ id, dst | (tab<<16) }; chunkstart[0..NCH_].
// ---------------------------------------------------------------------------
__global__ __launch_bounds__(512) void bucket_kernel(const int* __restrict__ ids,
                                                     const int* __restrict__ tabv,
                                                     int2* __restrict__ smeta,
                                                     int* __restrict__ chunkstart) {
    __shared__ int lcnt[512 * NCH_];
    __shared__ int segtot[NCH_][8];
    __shared__ int tot[NCH_];
    __shared__ int bbase[NCH_ + 1];
    const int t = threadIdx.x;

#pragma unroll
    for (int c = 0; c < NCH_; ++c) lcnt[t * NCH_ + c] = 0;
    __syncthreads();

    for (int p = t; p < NPAIR_; p += 512) {
        int id = ids[p];
        if (id != 0) lcnt[t * NCH_ + (id / CHUNK_)] += 1;
    }
    __syncthreads();

    if (t < NCH_ * 8) {
        int bkt = t >> 3, seg = t & 7;
        int run = 0;
        for (int i = 0; i < 64; ++i) {
            int idx = (seg * 64 + i) * NCH_ + bkt;
            int tmp = lcnt[idx];
            lcnt[idx] = run;
            run += tmp;
        }
        segtot[bkt][seg] = run;
    }
    __syncthreads();
    if (t < NCH_) {
        int run = 0;
#pragma unroll
        for (int s = 0; s < 8; ++s) { int tmp = segtot[t][s]; segtot[t][s] = run; run += tmp; }
        tot[t] = run;
    }
    __syncthreads();
    if (t == 0) {
        int run = 0;
#pragma unroll
        for (int c = 0; c < NCH_; ++c) { bbase[c] = run; run += tot[c]; }
        bbase[NCH_] = run;
#pragma unroll
        for (int c = 0; c <= NCH_; ++c) chunkstart[c] = bbase[c];
    }
    __syncthreads();
    if (t < NCH_ * 8) {
        int bkt = t >> 3, seg = t & 7;
        int add = segtot[bkt][seg];
        for (int i = 0; i < 64; ++i) lcnt[(seg * 64 + i) * NCH_ + bkt] += add;
    }
    __syncthreads();

    for (int p = t; p < NPAIR_; p += 512) {
        int id = ids[p];
        if (id == 0) continue;
        int bkt = id / CHUNK_;
        int pos = bbase[bkt] + lcnt[t * NCH_ + bkt];
        lcnt[t * NCH_ + bkt] += 1;
        int2 mm;
        mm.x = id;
        mm.y = p | (tabv[p] << 16);
        smeta[pos] = mm;
    }
}

// ---------------------------------------------------------------------------
// pair body: bit-identical arithmetic to all passing rounds
// ---------------------------------------------------------------------------
__device__ __forceinline__ void pair_body2(const int2 m, const float2* __restrict__ sb,
                                           int lo, const float2* __restrict__ trig,
                                           float* __restrict__ pcontrib) {
    int id  = m.x;
    int dst = m.y & 0xFFFF;
    int tab = m.y >> 16;
    float2 o = trig[tab];
    float2 g = sb[id - lo];
    float wabs = sqrtf(__fadd_rn(__fmul_rn(g.x, g.x), __fmul_rn(g.y, g.y)));
    float pre = __fadd_rn(__fmul_rn(g.x, o.x), __fmul_rn(g.y, o.y));
    float pim = __fsub_rn(__fmul_rn(g.y, o.x), __fmul_rn(g.x, o.y));
    if (pre < 1e-10f && pre > -1e-10f) pre = 1e-10f;
    if (pim < 1e-10f && pim > -1e-10f) pim = 1e-10f;
    float ang = fabsf(atan2f(pim, pre));
    pcontrib[dst] = __fadd_rn(wabs, ang);
}

// ---------------------------------------------------------------------------
// Kernel B: persistent, 1 block/CU. Wave 0 = DMA producer (global_load_lds,
// counted vmcnt(32) = 2 chunks in flight, dummy re-issues in tail keep counts
// exact). Waves 1-15 (960 thr) = consumers; their vmcnt queues hold ONLY
// smeta loads (compiler-derived waits). Barriers drain lgkm only.
// ---------------------------------------------------------------------------
__global__ __launch_bounds__(PFTH_, 1) void pf_kernel(const float* __restrict__ W,
                                                      const int2* __restrict__ smeta,
                                                      const int* __restrict__ chunkstart,
                                                      float* __restrict__ pfT) {
    extern __shared__ char smem[];
    float* pcontrib = (float*)smem;                        // [NPAIR_]
    char*  sbuf     = smem + PCON_BYTES_;                  // [4][16 KB]
    __shared__ int cstart[NCH_ + 1];
    __shared__ float2 trigS[121];

    const int t = threadIdx.x;
    const int kbase = blockIdx.x * KPB_;

    if (t <= NCH_) cstart[t] = chunkstart[t];
    if (t >= 128 && t < 128 + 121) {                       // init by wave 2 (not producer)
        int i = t - 128;
        int pp = i / 11 + 1, ss = i % 11 + 1;
        float pos = __fdiv_rn(__fmul_rn(PI_F, (float)pp), (float)ss);
        trigS[i] = make_float2(cosf(pos), sinf(pos));
    }
    __syncthreads();   // cstart/trigS visible before any use (R12 lesson)

    // DMA-stage chunk (cl,kl) into LDS buffer `buf`. Wave 0 only (t<64).
    // Always exactly 16 gload_lds (clamped addresses) -> exact vmcnt counts.
    auto stage = [&](int cl, int kl, int buf) {
        const int n16 = (cl == NCH_ - 1) ? TAILU_ : UNITS_;
        const char* gb = (const char*)W +
            ((size_t)(kbase + kl) * VOCAB_ + (size_t)cl * CHUNK_) * 8;
        char* lb = sbuf + (size_t)buf * (CHUNK_ * 8);
#pragma unroll
        for (int j = 0; j < 16; ++j) {
            int u = j * 64 + t;
            int uc = (u < n16) ? u : (n16 - 1);
            __builtin_amdgcn_global_load_lds(
                (const __attribute__((address_space(1))) void*)(gb + (size_t)uc * 16),
                (__attribute__((address_space(3))) void*)(lb + (size_t)j * 1024),
                16, 0, 0);
        }
    };

    int2 A0{}, A1{}, B0{}, B1{};
    const int ct = (t >= PRT_) ? (t - PRT_) : 0;

    // ---- prologue: stage chunks 0..2; consumers prefetch smeta(ch0)
    if (t < PRT_) {
        stage(0, 0, 0);
        stage(1, 0, 1);
        stage(2, 0, 2);
    } else {
        int q0 = ct;         if (q0 > NPAIR_ - 1) q0 = NPAIR_ - 1;
        int q1 = CNT_ + ct;  if (q1 > NPAIR_ - 1) q1 = NPAIR_ - 1;
        A0 = smeta[q0]; A1 = smeta[q1];
    }
    for (int i = t; i < NPAIR_; i += PFTH_) pcontrib[i] = 0.0f;

    int cc = 0, kk = 0;

#define PHASE(GG, CU0, CU1, NX0, NX1)                                            \
    {                                                                            \
        __builtin_amdgcn_sched_barrier(0);                                       \
        asm volatile("s_waitcnt lgkmcnt(0)" ::: "memory");                       \
        if (t < PRT_) { asm volatile("s_waitcnt vmcnt(32)" ::: "memory"); }      \
        __builtin_amdgcn_s_barrier();                                            \
        __builtin_amdgcn_sched_barrier(0);                                       \
        if (t < PRT_) {                                                          \
            int cl = cc + 3, kl = kk;                                            \
            if (cl >= NCH_) { cl -= NCH_; kl += 1; }                             \
            if ((GG) + 3 >= GTOT_) { cl = NCH_ - 1; kl = KPB_ - 1; }             \
            stage(cl, kl, ((GG) + 3) & 3);                                       \
        } else {                                                                 \
            {   int cn = cc + 1; if (cn >= NCH_) cn = 0;                         \
                int ns = cstart[cn];                                             \
                int q0 = ns + ct;         if (q0 > NPAIR_ - 1) q0 = NPAIR_ - 1;  \
                int q1 = ns + CNT_ + ct;  if (q1 > NPAIR_ - 1) q1 = NPAIR_ - 1;  \
                NX0 = smeta[q0]; NX1 = smeta[q1]; }                              \
            {   const float2* sb = (const float2*)(sbuf + (size_t)((GG) & 3) * (CHUNK_ * 8)); \
                const int lo = cc * CHUNK_;                                      \
                const int cs = cstart[cc], ce = cstart[cc + 1];                  \
                if (cs + ct < ce)         pair_body2(CU0, sb, lo, trigS, pcontrib); \
                if (cs + CNT_ + ct < ce)  pair_body2(CU1, sb, lo, trigS, pcontrib); \
                for (int pp = cs + 2 * CNT_ + ct; pp < ce; pp += CNT_)           \
                    pair_body2(smeta[pp], sb, lo, trigS, pcontrib); }            \
        }                                                                        \
        if (cc == NCH_ - 1) {                                                    \
            __builtin_amdgcn_sched_barrier(0);                                   \
            asm volatile("s_waitcnt lgkmcnt(0)" ::: "memory");                   \
            __builtin_amdgcn_s_barrier();                                        \
            __builtin_amdgcn_sched_barrier(0);                                   \
            if (t >= PRT_) {                                                     \
                float* outp = pfT + (size_t)(kbase + kk) * B_;                   \
                for (int bb = ct; bb < B_; bb += CNT_) {                         \
                    float acc = 0.0f;                                            \
                    _Pragma("unroll")                                            \
                    for (int w = 0; w < WIN_; ++w)                               \
                        acc = __fadd_rn(acc, pcontrib[bb * WIN_ + w]);           \
                    outp[bb] = acc;                                              \
                }                                                                \
            }                                                                    \
            cc = 0; ++kk;                                                        \
        } else { ++cc; }                                                         \
    }

#pragma unroll 1
    for (int g = 0; g < GTOT_; g += 2) {
        PHASE(g,     A0, A1, B0, B1)
        PHASE(g + 1, B0, B1, A0, A1)
    }
#undef PHASE
    // drain trailing (dummy) DMA before kernel end so the next kernel's LDS
    // can't be corrupted by late-landing writes
    asm volatile("s_waitcnt vmcnt(0) lgkmcnt(0)" ::: "memory");
}

// ---------------------------------------------------------------------------
// Kernel T: transpose [K,B] -> [B,K] via 64x64 LDS tiles
// ---------------------------------------------------------------------------
__global__ __launch_bounds__(256) void transpose_kb(const float* __restrict__ pfT,
                                                    float* __restrict__ pf) {
    __shared__ float tile[64][65];
    int kb = blockIdx.x * 64;
    int bb = blockIdx.y * 64;
    int tx = threadIdx.x & 63;
    int ty = threadIdx.x >> 6;
#pragma unroll
    for (int i = 0; i < 64; i += 4)
        tile[ty + i][tx] = pfT[(size_t)(kb + ty + i) * B_ + (bb + tx)];
    __syncthreads();
#pragma unroll
    for (int i = 0; i < 64; i += 4)
        pf[(size_t)(bb + ty + i) * K_ + (kb + tx)] = tile[tx][ty + i];
}

// ---------------------------------------------------------------------------
// Kernel C: per-row exact top-64 (radix select, jax tie semantics) + logits.
// ---------------------------------------------------------------------------
__global__ __launch_bounds__(256) void topk_logits_kernel(const float* __restrict__ pf,
                                                          const float* __restrict__ w_out,
                                                          const float* __restrict__ b_out,
                                                          float* __restrict__ out) {
    const int b = blockIdx.x;
    const int t = threadIdx.x;
    __shared__ uint32_t srow[K_];
    __shared__ int hist[256];
    __shared__ int sfx[256];
    __shared__ uint32_t sh_prefix;
    __shared__ int sh_need;
    __shared__ int wave_gt[4], wave_eq[4];
    __shared__ int gt_running, eq_running;
    __shared__ int idxlist[TOPK_];
    __shared__ float partial[4][NOUT_];

    const float* rowp = pf + (size_t)b * K_;
    for (int i = t; i < K_; i += 256) srow[i] = __float_as_uint(rowp[i]);
    if (t == 0) { sh_prefix = 0u; sh_need = TOPK_; gt_running = 0; eq_running = 0; }
    __syncthreads();

    for (int pass = 0; pass < 4; ++pass) {
        int shift = 24 - 8 * pass;
        uint32_t himask = (pass == 0) ? 0u : (0xFFFFFFFFu << (shift + 8));
        hist[t] = 0;
        __syncthreads();
        uint32_t prefix = sh_prefix & himask;
        for (int i = t; i < K_; i += 256) {
            uint32_t u = srow[i];
            if ((u & himask) == prefix) atomicAdd(&hist[(u >> shift) & 255], 1);
        }
        __syncthreads();
        sfx[t] = hist[t];
        __syncthreads();
#pragma unroll
        for (int off = 1; off < 256; off <<= 1) {
            int v = (t + off < 256) ? sfx[t + off] : 0;
            __syncthreads();
            sfx[t] += v;
            __syncthreads();
        }
        int need = sh_need;
        int above = (t == 255) ? 0 : sfx[t + 1];
        if (sfx[t] >= need && above < need) {
            sh_prefix |= ((uint32_t)t << shift);
            sh_need = need - above;
        }
        __syncthreads();
    }
    const uint32_t T = sh_prefix;
    const int r = sh_need;
    const int c_gt = TOPK_ - r;

    for (int cbase = 0; cbase < K_; cbase += 256) {
        uint32_t u = srow[cbase + t];
        bool gt = (u > T);
        bool eq = (u == T);
        unsigned long long mg = __ballot(gt);
        unsigned long long me = __ballot(eq);
        int lane = t & 63, wv = t >> 6;
        if (lane == 0) { wave_gt[wv] = __popcll(mg); wave_eq[wv] = __popcll(me); }
        __syncthreads();
        int offg = gt_running, offe = eq_running;
        for (int w2 = 0; w2 < wv; ++w2) { offg += wave_gt[w2]; offe += wave_eq[w2]; }
        unsigned long long lmask = (lane == 0) ? 0ull : ((~0ull) >> (64 - lane));
        int rkg = offg + __popcll(mg & lmask);
        int rke = offe + __popcll(me & lmask);
        if (gt) idxlist[rkg] = cbase + t;
        else if (eq && rke < r) idxlist[c_gt + rke] = cbase + t;
        __syncthreads();
        if (t == 0) {
            gt_running += wave_gt[0] + wave_gt[1] + wave_gt[2] + wave_gt[3];
            eq_running += wave_eq[0] + wave_eq[1] + wave_eq[2] + wave_eq[3];
        }
        __syncthreads();
    }

    {
        int lane = t & 63, wv4 = t >> 6;
        if (lane < NOUT_) {
            const float* wrow = w_out + (size_t)lane * K_;
            float s = 0.0f;
#pragma unroll
            for (int j = 0; j < TOPK_ / 4; ++j) s += wrow[idxlist[wv4 * (TOPK_ / 4) + j]];
            partial[wv4][lane] = s;
        }
        __syncthreads();
        if (t < NOUT_) {
            float s = b_out[t] + partial[0][t] + partial[1][t] + partial[2][t] + partial[3][t];
            out[b * NOUT_ + t] = s;
        }
    }
}

// ---------------------------------------------------------------------------
extern "C" void kernel_launch(void* const* d_in, const int* in_sizes, int n_in,
                              void* d_out, int out_size, void* d_ws, size_t ws_size,
                              hipStream_t stream) {
    const int*   ids   = (const int*)d_in[0];
    const float* W     = (const float*)d_in[1];
    const float* w_out = (const float*)d_in[2];
    const float* b_out = (const float*)d_in[3];
    float* out = (float*)d_out;

    char* ws = (char*)d_ws;
    const size_t pf_bytes = (size_t)K_ * B_ * sizeof(float);   // 33.55 MB
    float* pfT   = (float*)(ws);                               // [K, B]
    float* pf    = (float*)(ws + pf_bytes);                    // [B, K]
    int*   tabv  = (int*)(ws + 2 * pf_bytes);                  // [NPAIR_]
    int2*  smeta = (int2*)(ws + 2 * pf_bytes + 256 * 1024);    // [NPAIR_]
    int* chunkstart = (int*)(ws + 2 * pf_bytes + 768 * 1024);  // [NCH_+1]

    (void)hipFuncSetAttribute((const void*)pf_kernel,
                              hipFuncAttributeMaxDynamicSharedMemorySize,
                              SMEM_BYTES_);

    prep_kernel<<<(B_ + 255) / 256, 256, 0, stream>>>(ids, tabv);
    bucket_kernel<<<1, 512, 0, stream>>>(ids, tabv, smeta, chunkstart);
    pf_kernel<<<NBLK_, PFTH_, SMEM_BYTES_, stream>>>(W, smeta, chunkstart, pfT);
    transpose_kb<<<dim3(K_ / 64, B_ / 64), 256, 0, stream>>>(pfT, pf);
    topk_logits_kernel<<<B_, 256, 0, stream>>>(pf, w_out, b_out, out);
}

// Round 14
// 354.353 us; speedup vs baseline: 1.5535x; 1.2283x over previous
//
#include <hip/hip_runtime.h>
#include <hip/hip_bf16.h>
#include <stdint.h>

#define B_     2048
#define WIN_   11
#define K_     4096
#define VOCAB_ 30522
#define NOUT_  18
#define TOPK_  64
#define NPAIR_ (B_ * WIN_)         /* 22528 */
#define PI_F   3.14159274101257324f

#define KPB_   16                  /* k per persistent block */
#define NBLK_  (K_ / KPB_)         /* 256 blocks = 1 per CU */
#define PFTH_  1024
#define JPT_   (NPAIR_ / PFTH_)    /* 22 pairs per thread */
#define HB_    30720               /* hist bins (>= VOCAB_, 30*1024) */
#define PF_SMEM_   (NPAIR_ * 4)    /* 90112 B: pcontrib */
#define SORT_SMEM_ (HB_ * 4)       /* 122880 B: hist */

// ---------------------------------------------------------------------------
// Kernel A: per-batch window prep -> trig-table index per (b,w)
// ---------------------------------------------------------------------------
__global__ void prep_kernel(const int* __restrict__ ids, int* __restrict__ tabv) {
    int b = blockIdx.x * blockDim.x + threadIdx.x;
    if (b >= B_) return;
    const int* row = ids + b * WIN_;
    int poss[WIN_];
    int cnt = 0;
#pragma unroll
    for (int w = 0; w < WIN_; ++w) { cnt += (row[w] != 0); poss[w] = cnt; }
    int sl = (cnt > 0) ? cnt : WIN_;
#pragma unroll
    for (int w = 0; w < WIN_; ++w) {
        int tb = (poss[w] - 1) * 11 + (sl - 1);
        if (tb < 0) tb = 0;
        tabv[b * WIN_ + w] = tb;
    }
}

// ---------------------------------------------------------------------------
// Kernel S: counting sort of the (b,w) pairs by id (30522 bins, single block).
// ssmeta[pos] = int2{ id, dst | (tab<<16) }, pos in id-sorted order.
// Order within equal ids is non-deterministic (atomic) but output of pf is
// invariant to list order (each pair writes its own slot). Tail padded with
// a duplicate pair (harmless rewrite of same value).
// ---------------------------------------------------------------------------
__global__ __launch_bounds__(1024) void sort_kernel(const int* __restrict__ ids,
                                                    const int* __restrict__ tabv,
                                                    int2* __restrict__ ssmeta) {
    extern __shared__ int hist[];          // [HB_]
    __shared__ int partial[1024];
    __shared__ int totalNZ;
    const int t = threadIdx.x;

    for (int i = t; i < HB_; i += 1024) hist[i] = 0;
    __syncthreads();

    for (int p = t; p < NPAIR_; p += 1024) {
        int id = ids[p];
        if (id != 0) atomicAdd(&hist[id], 1);
    }
    __syncthreads();

    // blocked exclusive scan: thread t owns hist[30t .. 30t+30)
    const int base = 30 * t;
    int run = 0;
#pragma unroll
    for (int i = 0; i < 30; ++i) { int v = hist[base + i]; hist[base + i] = run; run += v; }
    partial[t] = run;
    __syncthreads();
    for (int off = 1; off < 1024; off <<= 1) {
        int v = (t >= off) ? partial[t - off] : 0;
        __syncthreads();
        partial[t] += v;
        __syncthreads();
    }
    int myBase = (t == 0) ? 0 : partial[t - 1];
    if (t == 1023) totalNZ = partial[1023];
#pragma unroll
    for (int i = 0; i < 30; ++i) hist[base + i] += myBase;
    __syncthreads();

    // scatter
    for (int p = t; p < NPAIR_; p += 1024) {
        int id = ids[p];
        if (id == 0) continue;
        int pos = atomicAdd(&hist[id], 1);
        int2 mm;
        mm.x = id;
        mm.y = p | (tabv[p] << 16);
        ssmeta[pos] = mm;
    }
    __threadfence();
    __syncthreads();
    // pad tail (only if some ids were 0; duplicate writes are value-identical)
    int nz = totalNZ;
    if (nz < NPAIR_) {
        int2 last = ssmeta[nz - 1];
        for (int p = nz + t; p < NPAIR_; p += 1024) ssmeta[p] = last;
    }
}

// ---------------------------------------------------------------------------
// pair body: bit-identical arithmetic to all passing rounds
// ---------------------------------------------------------------------------
__device__ __forceinline__ void pair_body3(const int2 m, const float2 g,
                                           const float2* __restrict__ trig,
                                           float* __restrict__ pcontrib) {
    int dst = m.y & 0xFFFF;
    int tab = m.y >> 16;
    float2 o = trig[tab];
    float wabs = sqrtf(__fadd_rn(__fmul_rn(g.x, g.x), __fmul_rn(g.y, g.y)));
    float pre = __fadd_rn(__fmul_rn(g.x, o.x), __fmul_rn(g.y, o.y));
    float pim = __fsub_rn(__fmul_rn(g.y, o.x), __fmul_rn(g.x, o.y));
    if (pre < 1e-10f && pre > -1e-10f) pre = 1e-10f;
    if (pim < 1e-10f && pim > -1e-10f) pim = 1e-10f;
    float ang = fabsf(atan2f(pim, pre));
    pcontrib[dst] = __fadd_rn(wabs, ang);
}

// ---------------------------------------------------------------------------
// Kernel B: persistent, 1 block/CU, NO LDS STAGING. Each thread holds its 22
// id-sorted pairs in registers; W gathered DIRECTLY from global (sorted ->
// quasi-sequential sweep, line-coalesced, each slice line fetched ~once/k).
// Two 11-deep gather batches ping-pong; next-k batch issued before the
// barrier (raw s_barrier + lgkm-only drain keeps them in flight).
// 2 barriers per k (32 total vs 240 staged phases).
// ---------------------------------------------------------------------------
__global__ __launch_bounds__(PFTH_) void pf_kernel(const float2* __restrict__ W2,
                                                   const int2* __restrict__ ssmeta,
                                                   float* __restrict__ pfT) {
    extern __shared__ char smem[];
    float* pcontrib = (float*)smem;        // [NPAIR_]
    __shared__ float2 trigS[121];

    const int t = threadIdx.x;
    const int kbase = blockIdx.x * KPB_;

    if (t < 121) {
        int pp = t / 11 + 1, ss = t % 11 + 1;
        float pos = __fdiv_rn(__fmul_rn(PI_F, (float)pp), (float)ss);
        trigS[t] = make_float2(cosf(pos), sinf(pos));
    }
    for (int i = t; i < NPAIR_; i += PFTH_) pcontrib[i] = 0.0f;

    // resident sorted pairs (compile-time indices -> registers)
    int2 mm[JPT_];
#pragma unroll
    for (int j = 0; j < JPT_; ++j) mm[j] = ssmeta[t + j * PFTH_];

    float2 gA[11], gB[11];
    {
        const float2* Wk = W2 + (size_t)kbase * VOCAB_;
#pragma unroll
        for (int j = 0; j < 11; ++j) gA[j] = Wk[mm[j].x];
    }
    __syncthreads();   // trig/pcontrib visible; one-time full drain is fine

#pragma unroll 1
    for (int kk = 0; kk < KPB_; ++kk) {
        const float2* Wk = W2 + (size_t)(kbase + kk) * VOCAB_;
        // issue second-half gathers for this k
#pragma unroll
        for (int j = 0; j < 11; ++j) gB[j] = Wk[mm[11 + j].x];
        // compute first half (gA ready; compiler waits counted vmcnt)
#pragma unroll
        for (int j = 0; j < 11; ++j) pair_body3(mm[j], gA[j], trigS, pcontrib);
        // issue first-half gathers for NEXT k (stay in flight across barrier)
        if (kk + 1 < KPB_) {
            const float2* Wn = W2 + (size_t)(kbase + kk + 1) * VOCAB_;
#pragma unroll
            for (int j = 0; j < 11; ++j) gA[j] = Wn[mm[j].x];
        }
        // compute second half
#pragma unroll
        for (int j = 0; j < 11; ++j) pair_body3(mm[11 + j], gB[j], trigS, pcontrib);

        // barrier 1: pcontrib writes visible (lgkm only; gathers keep flying)
        __builtin_amdgcn_sched_barrier(0);
        asm volatile("s_waitcnt lgkmcnt(0)" ::: "memory");
        __builtin_amdgcn_s_barrier();
        __builtin_amdgcn_sched_barrier(0);

        // per-k sum in exact w order -> pfT
        {
            float* outp = pfT + (size_t)(kbase + kk) * B_;
#pragma unroll
            for (int i = 0; i < B_ / PFTH_; ++i) {
                int bb = i * PFTH_ + t;
                float acc = 0.0f;
#pragma unroll
                for (int w = 0; w < WIN_; ++w)
                    acc = __fadd_rn(acc, pcontrib[bb * WIN_ + w]);
                outp[bb] = acc;
            }
        }
        // barrier 2: sums done before next k overwrites pcontrib
        __builtin_amdgcn_sched_barrier(0);
        asm volatile("s_waitcnt lgkmcnt(0)" ::: "memory");
        __builtin_amdgcn_s_barrier();
        __builtin_amdgcn_sched_barrier(0);
    }
}

// ---------------------------------------------------------------------------
// Kernel T: transpose [K,B] -> [B,K] via 64x64 LDS tiles
// ---------------------------------------------------------------------------
__global__ __launch_bounds__(256) void transpose_kb(const float* __restrict__ pfT,
                                                    float* __restrict__ pf) {
    __shared__ float tile[64][65];
    int kb = blockIdx.x * 64;
    int bb = blockIdx.y * 64;
    int tx = threadIdx.x & 63;
    int ty = threadIdx.x >> 6;
#pragma unroll
    for (int i = 0; i < 64; i += 4)
        tile[ty + i][tx] = pfT[(size_t)(kb + ty + i) * B_ + (bb + tx)];
    __syncthreads();
#pragma unroll
    for (int i = 0; i < 64; i += 4)
        pf[(size_t)(bb + ty + i) * K_ + (kb + tx)] = tile[tx][ty + i];
}

// ---------------------------------------------------------------------------
// Kernel C: per-row exact top-64 (radix select, jax tie semantics) + logits.
// ---------------------------------------------------------------------------
__global__ __launch_bounds__(256) void topk_logits_kernel(const float* __restrict__ pf,
                                                          const float* __restrict__ w_out,
                                                          const float* __restrict__ b_out,
                                                          float* __restrict__ out) {
    const int b = blockIdx.x;
    const int t = threadIdx.x;
    __shared__ uint32_t srow[K_];
    __shared__ int hist[256];
    __shared__ int sfx[256];
    __shared__ uint32_t sh_prefix;
    __shared__ int sh_need;
    __shared__ int wave_gt[4], wave_eq[4];
    __shared__ int gt_running, eq_running;
    __shared__ int idxlist[TOPK_];
    __shared__ float partial[4][NOUT_];

    const float* rowp = pf + (size_t)b * K_;
    for (int i = t; i < K_; i += 256) srow[i] = __float_as_uint(rowp[i]);
    if (t == 0) { sh_prefix = 0u; sh_need = TOPK_; gt_running = 0; eq_running = 0; }
    __syncthreads();

    for (int pass = 0; pass < 4; ++pass) {
        int shift = 24 - 8 * pass;
        uint32_t himask = (pass == 0) ? 0u : (0xFFFFFFFFu << (shift + 8));
        hist[t] = 0;
        __syncthreads();
        uint32_t prefix = sh_prefix & himask;
        for (int i = t; i < K_; i += 256) {
            uint32_t u = srow[i];
            if ((u & himask) == prefix) atomicAdd(&hist[(u >> shift) & 255], 1);
        }
        __syncthreads();
        sfx[t] = hist[t];
        __syncthreads();
#pragma unroll
        for (int off = 1; off < 256; off <<= 1) {
            int v = (t + off < 256) ? sfx[t + off] : 0;
            __syncthreads();
            sfx[t] += v;
            __syncthreads();
        }
        int need = sh_need;
        int above = (t == 255) ? 0 : sfx[t + 1];
        if (sfx[t] >= need && above < need) {
            sh_prefix |= ((uint32_t)t << shift);
            sh_need = need - above;
        }
        __syncthreads();
    }
    const uint32_t T = sh_prefix;
    const int r = sh_need;
    const int c_gt = TOPK_ - r;

    for (int cbase = 0; cbase < K_; cbase += 256) {
        uint32_t u = srow[cbase + t];
        bool gt = (u > T);
        bool eq = (u == T);
        unsigned long long mg = __ballot(gt);
        unsigned long long me = __ballot(eq);
        int lane = t & 63, wv = t >> 6;
        if (lane == 0) { wave_gt[wv] = __popcll(mg); wave_eq[wv] = __popcll(me); }
        __syncthreads();
        int offg = gt_running, offe = eq_running;
        for (int w2 = 0; w2 < wv; ++w2) { offg += wave_gt[w2]; offe += wave_eq[w2]; }
        unsigned long long lmask = (lane == 0) ? 0ull : ((~0ull) >> (64 - lane));
        int rkg = offg + __popcll(mg & lmask);
        int rke = offe + __popcll(me & lmask);
        if (gt) idxlist[rkg] = cbase + t;
        else if (eq && rke < r) idxlist[c_gt + rke] = cbase + t;
        __syncthreads();
        if (t == 0) {
            gt_running += wave_gt[0] + wave_gt[1] + wave_gt[2] + wave_gt[3];
            eq_running += wave_eq[0] + wave_eq[1] + wave_eq[2] + wave_eq[3];
        }
        __syncthreads();
    }

    {
        int lane = t & 63, wv4 = t >> 6;
        if (lane < NOUT_) {
            const float* wrow = w_out + (size_t)lane * K_;
            float s = 0.0f;
#pragma unroll
            for (int j = 0; j < TOPK_ / 4; ++j) s += wrow[idxlist[wv4 * (TOPK_ / 4) + j]];
            partial[wv4][lane] = s;
        }
        __syncthreads();
        if (t < NOUT_) {
            float s = b_out[t] + partial[0][t] + partial[1][t] + partial[2][t] + partial[3][t];
            out[b * NOUT_ + t] = s;
        }
    }
}

// ---------------------------------------------------------------------------
extern "C" void kernel_launch(void* const* d_in, const int* in_sizes, int n_in,
                              void* d_out, int out_size, void* d_ws, size_t ws_size,
                              hipStream_t stream) {
    const int*   ids   = (const int*)d_in[0];
    const float* W     = (const float*)d_in[1];
    const float* w_out = (const float*)d_in[2];
    const float* b_out = (const float*)d_in[3];
    float* out = (float*)d_out;

    char* ws = (char*)d_ws;
    const size_t pf_bytes = (size_t)K_ * B_ * sizeof(float);   // 33.55 MB
    float* pfT    = (float*)(ws);                              // [K, B]
    float* pf     = (float*)(ws + pf_bytes);                   // [B, K]
    int*   tabv   = (int*)(ws + 2 * pf_bytes);                 // [NPAIR_]
    int2*  ssmeta = (int2*)(ws + 2 * pf_bytes + 256 * 1024);   // [NPAIR_]

    (void)hipFuncSetAttribute((const void*)pf_kernel,
                              hipFuncAttributeMaxDynamicSharedMemorySize,
                              PF_SMEM_);
    (void)hipFuncSetAttribute((const void*)sort_kernel,
                              hipFuncAttributeMaxDynamicSharedMemorySize,
                              SORT_SMEM_);

    prep_kernel<<<(B_ + 255) / 256, 256, 0, stream>>>(ids, tabv);
    sort_kernel<<<1, 1024, SORT_SMEM_, stream>>>(ids, tabv, ssmeta);
    pf_kernel<<<NBLK_, PFTH_, PF_SMEM_, stream>>>((const float2*)W, ssmeta, pfT);
    transpose_kb<<<dim3(K_ / 64, B_ / 64), 256, 0, stream>>>(pfT, pf);
    topk_logits_kernel<<<B_, 256, 0, stream>>>(pf, w_out, b_out, out);
}

// Round 15
// 350.357 us; speedup vs baseline: 1.5713x; 1.0114x over previous
//
#include <hip/hip_runtime.h>
#include <hip/hip_bf16.h>
#include <stdint.h>

#define B_     2048
#define WIN_   11
#define K_     4096
#define VOCAB_ 30522
#define NOUT_  18
#define TOPK_  64
#define NPAIR_ (B_ * WIN_)         /* 22528 */
#define PI_F   3.14159274101257324f

#define KPB_   16                  /* k per persistent block */
#define NBLK_  (K_ / KPB_)         /* 256 blocks = 1 per CU */
#define PFTH_  1024
#define JPT_   (NPAIR_ / PFTH_)    /* 22 pairs per thread */
#define HB_    30720               /* hist bins (>= VOCAB_) */
#define PF_SMEM_   (NPAIR_ * 4)    /* 90112 B: pcontrib */
#define SORT_SMEM_ (HB_ * 4)       /* 122880 B: hist */

// ---------------------------------------------------------------------------
// Kernel A: per-batch window prep -> trig-table index per (b,w)
// ---------------------------------------------------------------------------
__global__ void prep_kernel(const int* __restrict__ ids, int* __restrict__ tabv) {
    int b = blockIdx.x * blockDim.x + threadIdx.x;
    if (b >= B_) return;
    const int* row = ids + b * WIN_;
    int poss[WIN_];
    int cnt = 0;
#pragma unroll
    for (int w = 0; w < WIN_; ++w) { cnt += (row[w] != 0); poss[w] = cnt; }
    int sl = (cnt > 0) ? cnt : WIN_;
#pragma unroll
    for (int w = 0; w < WIN_; ++w) {
        int tb = (poss[w] - 1) * 11 + (sl - 1);
        if (tb < 0) tb = 0;
        tabv[b * WIN_ + w] = tb;
    }
}

// ---------------------------------------------------------------------------
// Kernel S: counting sort of the (b,w) pairs by id (single block).
// ssmeta[pos] = int2{ id, dst | (tab<<16) }, id-sorted. pf output is
// invariant to within-id order (single writer per slot).
// ---------------------------------------------------------------------------
__global__ __launch_bounds__(1024) void sort_kernel(const int* __restrict__ ids,
                                                    const int* __restrict__ tabv,
                                                    int2* __restrict__ ssmeta) {
    extern __shared__ int hist[];          // [HB_]
    __shared__ int partial[1024];
    __shared__ int totalNZ;
    const int t = threadIdx.x;

    for (int i = t; i < HB_; i += 1024) hist[i] = 0;
    __syncthreads();

    for (int p = t; p < NPAIR_; p += 1024) {
        int id = ids[p];
        if (id != 0) atomicAdd(&hist[id], 1);
    }
    __syncthreads();

    const int base = 30 * t;
    int run = 0;
#pragma unroll
    for (int i = 0; i < 30; ++i) { int v = hist[base + i]; hist[base + i] = run; run += v; }
    partial[t] = run;
    __syncthreads();
    for (int off = 1; off < 1024; off <<= 1) {
        int v = (t >= off) ? partial[t - off] : 0;
        __syncthreads();
        partial[t] += v;
        __syncthreads();
    }
    int myBase = (t == 0) ? 0 : partial[t - 1];
    if (t == 1023) totalNZ = partial[1023];
#pragma unroll
    for (int i = 0; i < 30; ++i) hist[base + i] += myBase;
    __syncthreads();

    for (int p = t; p < NPAIR_; p += 1024) {
        int id = ids[p];
        if (id == 0) continue;
        int pos = atomicAdd(&hist[id], 1);
        int2 mm;
        mm.x = id;
        mm.y = p | (tabv[p] << 16);
        ssmeta[pos] = mm;
    }
    __threadfence();
    __syncthreads();
    int nz = totalNZ;
    if (nz < NPAIR_) {
        int2 last = ssmeta[nz - 1];
        for (int p = nz + t; p < NPAIR_; p += 1024) ssmeta[p] = last;
    }
}

// ---------------------------------------------------------------------------
// pair body: bit-identical arithmetic to all passing rounds
// ---------------------------------------------------------------------------
__device__ __forceinline__ void pair_body3(const int2 m, const float2 g,
                                           const float2* __restrict__ trig,
                                           float* __restrict__ pcontrib) {
    int dst = m.y & 0xFFFF;
    int tab = m.y >> 16;
    float2 o = trig[tab];
    float wabs = sqrtf(__fadd_rn(__fmul_rn(g.x, g.x), __fmul_rn(g.y, g.y)));
    float pre = __fadd_rn(__fmul_rn(g.x, o.x), __fmul_rn(g.y, o.y));
    float pim = __fsub_rn(__fmul_rn(g.y, o.x), __fmul_rn(g.x, o.y));
    if (pre < 1e-10f && pre > -1e-10f) pre = 1e-10f;
    if (pim < 1e-10f && pim > -1e-10f) pim = 1e-10f;
    float ang = fabsf(atan2f(pim, pre));
    pcontrib[dst] = __fadd_rn(wabs, ang);
}

// ---------------------------------------------------------------------------
// Kernel B: persistent, 1 block/CU, no staging. R15 change vs R14: BOTH
// gather batches (gA and gB) are now issued a FULL k-phase ahead (gB(k+1)
// issued at end of phase k, not gB(k) at its start) -> every gather has
// ~10 us prefetch slack; no exposed miss latency. Same registers (gA,gB
// both live through the phase either way). 2 lgkm-only barriers per k.
// ---------------------------------------------------------------------------
__global__ __launch_bounds__(PFTH_) void pf_kernel(const float2* __restrict__ W2,
                                                   const int2* __restrict__ ssmeta,
                                                   float* __restrict__ pfT) {
    extern __shared__ char smem[];
    float* pcontrib = (float*)smem;        // [NPAIR_]
    __shared__ float2 trigS[121];

    const int t = threadIdx.x;
    const int kbase = blockIdx.x * KPB_;

    if (t < 121) {
        int pp = t / 11 + 1, ss = t % 11 + 1;
        float pos = __fdiv_rn(__fmul_rn(PI_F, (float)pp), (float)ss);
        trigS[t] = make_float2(cosf(pos), sinf(pos));
    }
    for (int i = t; i < NPAIR_; i += PFTH_) pcontrib[i] = 0.0f;

    int2 mm[JPT_];
#pragma unroll
    for (int j = 0; j < JPT_; ++j) mm[j] = ssmeta[t + j * PFTH_];

    float2 gA[11], gB[11];
    {   // prologue: both batches of k=0 issued here (full prefetch from start)
        const float2* Wk = W2 + (size_t)kbase * VOCAB_;
#pragma unroll
        for (int j = 0; j < 11; ++j) gA[j] = Wk[mm[j].x];
#pragma unroll
        for (int j = 0; j < 11; ++j) gB[j] = Wk[mm[11 + j].x];
    }
    __syncthreads();

#pragma unroll 1
    for (int kk = 0; kk < KPB_; ++kk) {
        const float2* Wn = W2 + (size_t)(kbase + kk + 1) * VOCAB_;
        // compute first half (gA(k): prefetched one full phase ago)
#pragma unroll
        for (int j = 0; j < 11; ++j) pair_body3(mm[j], gA[j], trigS, pcontrib);
        // issue gA(k+1)
        if (kk + 1 < KPB_) {
#pragma unroll
            for (int j = 0; j < 11; ++j) gA[j] = Wn[mm[j].x];
        }
        // compute second half (gB(k): prefetched one full phase ago)
#pragma unroll
        for (int j = 0; j < 11; ++j) pair_body3(mm[11 + j], gB[j], trigS, pcontrib);
        // issue gB(k+1)
        if (kk + 1 < KPB_) {
#pragma unroll
            for (int j = 0; j < 11; ++j) gB[j] = Wn[mm[11 + j].x];
        }

        // barrier 1: pcontrib writes visible (lgkm only; 22 gathers in flight)
        __builtin_amdgcn_sched_barrier(0);
        asm volatile("s_waitcnt lgkmcnt(0)" ::: "memory");
        __builtin_amdgcn_s_barrier();
        __builtin_amdgcn_sched_barrier(0);

        // per-k sum in exact w order -> pfT
        {
            float* outp = pfT + (size_t)(kbase + kk) * B_;
#pragma unroll
            for (int i = 0; i < B_ / PFTH_; ++i) {
                int bb = i * PFTH_ + t;
                float acc = 0.0f;
#pragma unroll
                for (int w = 0; w < WIN_; ++w)
                    acc = __fadd_rn(acc, pcontrib[bb * WIN_ + w]);
                outp[bb] = acc;
            }
        }
        // barrier 2: sums done before next k overwrites pcontrib
        __builtin_amdgcn_sched_barrier(0);
        asm volatile("s_waitcnt lgkmcnt(0)" ::: "memory");
        __builtin_amdgcn_s_barrier();
        __builtin_amdgcn_sched_barrier(0);
    }
}

// ---------------------------------------------------------------------------
// Kernel T: transpose [K,B] -> [B,K] via 64x64 LDS tiles
// ---------------------------------------------------------------------------
__global__ __launch_bounds__(256) void transpose_kb(const float* __restrict__ pfT,
                                                    float* __restrict__ pf) {
    __shared__ float tile[64][65];
    int kb = blockIdx.x * 64;
    int bb = blockIdx.y * 64;
    int tx = threadIdx.x & 63;
    int ty = threadIdx.x >> 6;
#pragma unroll
    for (int i = 0; i < 64; i += 4)
        tile[ty + i][tx] = pfT[(size_t)(kb + ty + i) * B_ + (bb + tx)];
    __syncthreads();
#pragma unroll
    for (int i = 0; i < 64; i += 4)
        pf[(size_t)(bb + ty + i) * K_ + (kb + tx)] = tile[tx][ty + i];
}

// ---------------------------------------------------------------------------
// Kernel C: per-row exact top-64 (radix select, jax tie semantics) + logits.
// ---------------------------------------------------------------------------
__global__ __launch_bounds__(256) void topk_logits_kernel(const float* __restrict__ pf,
                                                          const float* __restrict__ w_out,
                                                          const float* __restrict__ b_out,
                                                          float* __restrict__ out) {
    const int b = blockIdx.x;
    const int t = threadIdx.x;
    __shared__ uint32_t srow[K_];
    __shared__ int hist[256];
    __shared__ int sfx[256];
    __shared__ uint32_t sh_prefix;
    __shared__ int sh_need;
    __shared__ int wave_gt[4], wave_eq[4];
    __shared__ int gt_running, eq_running;
    __shared__ int idxlist[TOPK_];
    __shared__ float partial[4][NOUT_];

    const float* rowp = pf + (size_t)b * K_;
    for (int i = t; i < K_; i += 256) srow[i] = __float_as_uint(rowp[i]);
    if (t == 0) { sh_prefix = 0u; sh_need = TOPK_; gt_running = 0; eq_running = 0; }
    __syncthreads();

    for (int pass = 0; pass < 4; ++pass) {
        int shift = 24 - 8 * pass;
        uint32_t himask = (pass == 0) ? 0u : (0xFFFFFFFFu << (shift + 8));
        hist[t] = 0;
        __syncthreads();
        uint32_t prefix = sh_prefix & himask;
        for (int i = t; i < K_; i += 256) {
            uint32_t u = srow[i];
            if ((u & himask) == prefix) atomicAdd(&hist[(u >> shift) & 255], 1);
        }
        __syncthreads();
        sfx[t] = hist[t];
        __syncthreads();
#pragma unroll
        for (int off = 1; off < 256; off <<= 1) {
            int v = (t + off < 256) ? sfx[t + off] : 0;
            __syncthreads();
            sfx[t] += v;
            __syncthreads();
        }
        int need = sh_need;
        int above = (t == 255) ? 0 : sfx[t + 1];
        if (sfx[t] >= need && above < need) {
            sh_prefix |= ((uint32_t)t << shift);
            sh_need = need - above;
        }
        __syncthreads();
    }
    const uint32_t T = sh_prefix;
    const int r = sh_need;
    const int c_gt = TOPK_ - r;

    for (int cbase = 0; cbase < K_; cbase += 256) {
        uint32_t u = srow[cbase + t];
        bool gt = (u > T);
        bool eq = (u == T);
        unsigned long long mg = __ballot(gt);
        unsigned long long me = __ballot(eq);
        int lane = t & 63, wv = t >> 6;
        if (lane == 0) { wave_gt[wv] = __popcll(mg); wave_eq[wv] = __popcll(me); }
        __syncthreads();
        int offg = gt_running, offe = eq_running;
        for (int w2 = 0; w2 < wv; ++w2) { offg += wave_gt[w2]; offe += wave_eq[w2]; }
        unsigned long long lmask = (lane == 0) ? 0ull : ((~0ull) >> (64 - lane));
        int rkg = offg + __popcll(mg & lmask);
        int rke = offe + __popcll(me & lmask);
        if (gt) idxlist[rkg] = cbase + t;
        else if (eq && rke < r) idxlist[c_gt + rke] = cbase + t;
        __syncthreads();
        if (t == 0) {
            gt_running += wave_gt[0] + wave_gt[1] + wave_gt[2] + wave_gt[3];
            eq_running += wave_eq[0] + wave_eq[1] + wave_eq[2] + wave_eq[3];
        }
        __syncthreads();
    }

    {
        int lane = t & 63, wv4 = t >> 6;
        if (lane < NOUT_) {
            const float* wrow = w_out + (size_t)lane * K_;
            float s = 0.0f;
#pragma unroll
            for (int j = 0; j < TOPK_ / 4; ++j) s += wrow[idxlist[wv4 * (TOPK_ / 4) + j]];
            partial[wv4][lane] = s;
        }
        __syncthreads();
        if (t < NOUT_) {
            float s = b_out[t] + partial[0][t] + partial[1][t] + partial[2][t] + partial[3][t];
            out[b * NOUT_ + t] = s;
        }
    }
}

// ---------------------------------------------------------------------------
extern "C" void kernel_launch(void* const* d_in, const int* in_sizes, int n_in,
                              void* d_out, int out_size, void* d_ws, size_t ws_size,
                              hipStream_t stream) {
    const int*   ids   = (const int*)d_in[0];
    const float* W     = (const float*)d_in[1];
    const float* w_out = (const float*)d_in[2];
    const float* b_out = (const float*)d_in[3];
    float* out = (float*)d_out;

    char* ws = (char*)d_ws;
    const size_t pf_bytes = (size_t)K_ * B_ * sizeof(float);   // 33.55 MB
    float* pfT    = (float*)(ws);                              // [K, B]
    float* pf     = (float*)(ws + pf_bytes);                   // [B, K]
    int*   tabv   = (int*)(ws + 2 * pf_bytes);                 // [NPAIR_]
    int2*  ssmeta = (int2*)(ws + 2 * pf_bytes + 256 * 1024);   // [NPAIR_]

    (void)hipFuncSetAttribute((const void*)pf_kernel,
                              hipFuncAttributeMaxDynamicSharedMemorySize,
                              PF_SMEM_);
    (void)hipFuncSetAttribute((const void*)sort_kernel,
                              hipFuncAttributeMaxDynamicSharedMemorySize,
                              SORT_SMEM_);

    prep_kernel<<<(B_ + 255) / 256, 256, 0, stream>>>(ids, tabv);
    sort_kernel<<<1, 1024, SORT_SMEM_, stream>>>(ids, tabv, ssmeta);
    pf_kernel<<<NBLK_, PFTH_, PF_SMEM_, stream>>>((const float2*)W, ssmeta, pfT);
    transpose_kb<<<dim3(K_ / 64, B_ / 64), 256, 0, stream>>>(pfT, pf);
    topk_logits_kernel<<<B_, 256, 0, stream>>>(pf, w_out, b_out, out);
}